// Round 8
// baseline (213.783 us; speedup 1.0000x reference)
//
#include <hip/hip_runtime.h>
#include <hip/hip_bf16.h>
#include <hip/hip_fp8.h>

// SimCLR NT-Xent loss on MI355X.
// loss = -(1/2B) sum_t [ 10*G[t,j0(t)] - (10 + log sum_{j!=t} exp(10*G[t,j]-10)) ]
// where G = M M^T, M = l2norm rows of [z_i; z_j], j0 = (t%B==0) ? 1 : 0.
// Round 8: round-7 structure (MX fp8 16x16x128, scale=1.0, b64 LDS reads,
// half-swapped storage -> 0 bank conflicts, verified) with the operand
// assembly rewritten as int2v loads + element inserts. Round 7's
// union{long[4];int8v} defeated SROA -> 545 MB of scratch traffic
// (WRITE_SIZE 316 MB, MfmaUtil 0.09%). Pure-SSA assembly fixes codegen.

#define BB 4096      // batch B
#define DD 512       // feature dim (bytes per row in fp8)
#define NN 8192      // 2B rows of G
#define TILE 128     // block tile (rows x cols)
#define KB 128       // K bytes (=elements) staged per LDS chunk
#define NBLK 2080    // 64*65/2 upper-triangle block tiles

typedef __attribute__((ext_vector_type(2))) int   int2v;   // 8 B
typedef __attribute__((ext_vector_type(8))) int   int8v;   // 32 B (8 VGPR)
typedef __attribute__((ext_vector_type(4))) float f32x4;

#define AS1 __attribute__((address_space(1)))
#define AS3 __attribute__((address_space(3)))
static __device__ __forceinline__ void gload_lds16(const void* g, void* l) {
    __builtin_amdgcn_global_load_lds((const AS1 void*)g, (AS3 void*)l, 16, 0, 0);
}

// ---------------- kernel 1: L2-normalize rows, cast to fp8; zero rowsum ----
// One wave per row. M layout: row r, granule g (16 B), 8 B halves swapped
// when (r>>3)&1 -- lets gram's b64 fragment reads spread banks via row bit 3.
__global__ __launch_bounds__(256)
void normalize_kernel(const float* __restrict__ zi, const float* __restrict__ zj,
                      unsigned char* __restrict__ M, float* __restrict__ rowsum) {
    const int wave = threadIdx.x >> 6;
    const int lane = threadIdx.x & 63;
    const int row  = blockIdx.x * 4 + wave;      // 2048 blocks * 4 rows
    if (threadIdx.x < 4) rowsum[blockIdx.x * 4 + threadIdx.x] = 0.f;
    const float* src = (row < BB) ? (zi + (size_t)row * DD)
                                  : (zj + (size_t)(row - BB) * DD);
    float4 v0 = ((const float4*)src)[lane * 2 + 0];
    float4 v1 = ((const float4*)src)[lane * 2 + 1];
    float ss = v0.x*v0.x + v0.y*v0.y + v0.z*v0.z + v0.w*v0.w
             + v1.x*v1.x + v1.y*v1.y + v1.z*v1.z + v1.w*v1.w;
    #pragma unroll
    for (int off = 1; off <= 32; off <<= 1) ss += __shfl_xor(ss, off);
    const float inv = rsqrtf(ss);
    const float vals[8] = {v0.x*inv, v0.y*inv, v0.z*inv, v0.w*inv,
                           v1.x*inv, v1.y*inv, v1.z*inv, v1.w*inv};
    union { long u; unsigned char b[8]; } pk;
    #pragma unroll
    for (int j = 0; j < 8; ++j)
        pk.b[j] = __hip_cvt_float_to_fp8(vals[j], __HIP_SATFINITE, __HIP_E4M3);
    const int swp = (row >> 3) & 1;              // half-swap inside each granule
    ((long*)(M + (size_t)row * DD))[lane ^ swp] = pk.u;
}

// ---------------- kernel 2: Gram tile + exp row/col sums -------------------
// 2080 blocks, one upper-triangle 128x128 tile each (by >= bx).
// Wave w: rows wr=(w>>1)*64, cols wc=(w&1)*64; 4x4 of 16x16 MFMA tiles,
// one K=128 scaled MFMA per tile per chunk.
// LDS: row-major 128 rows x 128 B, XOR-swizzled 16B granules
//   granule q holds (row=q>>3, g=(q&7)^((q>>3)&7)); gather side inverts the
//   swizzle so global_load_lds's lane-linear dest constraint is satisfied.
__global__ __launch_bounds__(256, 3)
void gram_lse_kernel(const unsigned char* __restrict__ Mg,
                     float* __restrict__ rowsum, float* __restrict__ targets) {
    __shared__ __align__(16) char As[TILE * KB];   // 16 KB
    __shared__ __align__(16) char Bs[TILE * KB];   // 16 KB

    // XCD-banded order: dispatch d -> band d%8 (one XCD), 260 tiles per band.
    const int d = blockIdx.x;
    const int p = (d & 7) * 260 + (d >> 3);
    // triangular decode: p -> (bx, by) with by >= bx
    int by = (int)((sqrtf(8.0f * (float)p + 1.0f) - 1.0f) * 0.5f);
    while ((by + 1) * (by + 2) / 2 <= p) ++by;
    while (by * (by + 1) / 2 > p) --by;
    const int bx = p - by * (by + 1) / 2;

    const int rowBase = bx * TILE;
    const int colBase = by * TILE;
    const bool diag = (bx == by);
    const int tid  = threadIdx.x;
    const int wave = tid >> 6;
    const int lane = tid & 63;
    const int wr = (wave >> 1) * 64;
    const int wc = (wave & 1) * 64;
    const int l15 = lane & 15;
    const int l4  = lane >> 4;          // quad 0..3 (k-window selector)
    const int r7  = l15 & 7;
    const int r3  = (l15 >> 3) & 1;     // row bit 3 -> half-swap key

    // staging gather pattern (constant per thread across issues & k0):
    const int sg  = (tid & 7) ^ ((tid >> 3) & 7);   // source granule within row
    const int sr0 = tid >> 3;                        // source row base (+32/issue)
    const unsigned char* gA0 = Mg + (size_t)(rowBase + sr0) * DD + sg * 16;
    const unsigned char* gB0 = Mg + (size_t)(colBase + sr0) * DD + sg * 16;
    char* lA0 = As + tid * 16;                       // granule q = tid (+256/issue)
    char* lB0 = Bs + tid * 16;

    // fragment addressing: operand row = base+l15, lane k-window = l4*32
    //   -> granules {2*l4, 2*l4+1} (XOR r7), halves XOR r3 (storage half-swap).
    // Per b64: conflict-free (round-7 dispatch measured SQ_LDS_BANK_CONFLICT=0).
    const int g0off = (((2 * l4 + 0) ^ r7) << 4) | (r3 << 3);
    const int g1off = (((2 * l4 + 1) ^ r7) << 4) | (r3 << 3);
    const int arow0 = (wr + l15) * KB;
    const int brow0 = (wc + l15) * KB;
    const char* BsP = diag ? As : Bs;

    f32x4 acc[4][4] = {};

    for (int k0 = 0; k0 < DD; k0 += KB) {
        __syncthreads();   // previous-iteration LDS reads done
        #pragma unroll
        for (int i = 0; i < 4; ++i)
            gload_lds16(gA0 + k0 + (size_t)i * 32 * DD, lA0 + i * 4096);
        if (!diag) {
            #pragma unroll
            for (int i = 0; i < 4; ++i)
                gload_lds16(gB0 + k0 + (size_t)i * 32 * DD, lB0 + i * 4096);
        }
        __syncthreads();   // drains vmcnt(0): staging complete

        // Operand assembly: logical byte order (g0:h0, g0:h1, g1:h0, g1:h1);
        // stored half at offset (j^r3)*8 is logical half j, so g0off^8 flips
        // to the other logical half. Pure SSA (no unions -> no scratch).
        int8v a[4], b[4];
        #pragma unroll
        for (int mi = 0; mi < 4; ++mi) {
            const char* base = As + arow0 + mi * 2048;
            int2v w0 = *(const int2v*)(base + g0off);
            int2v w1 = *(const int2v*)(base + (g0off ^ 8));
            int2v w2 = *(const int2v*)(base + g1off);
            int2v w3 = *(const int2v*)(base + (g1off ^ 8));
            int8v t;
            t[0] = w0[0]; t[1] = w0[1]; t[2] = w1[0]; t[3] = w1[1];
            t[4] = w2[0]; t[5] = w2[1]; t[6] = w3[0]; t[7] = w3[1];
            a[mi] = t;
        }
        #pragma unroll
        for (int ni = 0; ni < 4; ++ni) {
            const char* base = BsP + brow0 + ni * 2048;
            int2v w0 = *(const int2v*)(base + g0off);
            int2v w1 = *(const int2v*)(base + (g0off ^ 8));
            int2v w2 = *(const int2v*)(base + g1off);
            int2v w3 = *(const int2v*)(base + (g1off ^ 8));
            int8v t;
            t[0] = w0[0]; t[1] = w0[1]; t[2] = w1[0]; t[3] = w1[1];
            t[4] = w2[0]; t[5] = w2[1]; t[6] = w3[0]; t[7] = w3[1];
            b[ni] = t;
        }
        #pragma unroll
        for (int mi = 0; mi < 4; ++mi)
            #pragma unroll
            for (int ni = 0; ni < 4; ++ni)
                acc[mi][ni] = __builtin_amdgcn_mfma_scale_f32_16x16x128_f8f6f4(
                    a[mi], b[ni], acc[mi][ni],
                    0, 0,          // fmtA=fp8, fmtB=fp8
                    0, 127,        // scaleA: E8M0 127 = 1.0
                    0, 127);       // scaleB: 1.0
    }

    // ---- epilogue ----
    // C/D layout: col = lane&15, row = (lane>>4)*4 + reg  (dtype-independent)
    float cs[4] = {0.f, 0.f, 0.f, 0.f};   // column partials (off-diag tiles)
    #pragma unroll
    for (int mi = 0; mi < 4; ++mi) {
        float rs[4] = {0.f, 0.f, 0.f, 0.f};
        #pragma unroll
        for (int ni = 0; ni < 4; ++ni) {
            const int gcol = colBase + wc + ni * 16 + l15;
            #pragma unroll
            for (int r = 0; r < 4; ++r) {
                const int grow = rowBase + wr + mi * 16 + l4 * 4 + r;
                float logit = 10.f * acc[mi][ni][r];
                float e = __expf(logit - 10.f);
                if (grow == gcol) e = 0.f;     // exclude diagonal exactly
                rs[r] += e;
                cs[ni] += e;
                // targets: rows 0/1 of G give 10*G[t, j0] transposed.
                // Only bx==0 blocks write; disjoint col ranges -> plain store.
                if (rowBase == 0 && grow < 2) {
                    const int j0 = ((gcol & (BB - 1)) == 0) ? 1 : 0;
                    if (grow == j0) targets[gcol] = logit;
                }
            }
        }
        #pragma unroll
        for (int m = 1; m <= 8; m <<= 1)
            #pragma unroll
            for (int r = 0; r < 4; ++r)
                rs[r] += __shfl_xor(rs[r], m);
        if (l15 == 0) {
            #pragma unroll
            for (int r = 0; r < 4; ++r)
                atomicAdd(&rowsum[rowBase + wr + mi * 16 + l4 * 4 + r], rs[r]);
        }
    }
    if (!diag) {
        #pragma unroll
        for (int ni = 0; ni < 4; ++ni) {
            cs[ni] += __shfl_xor(cs[ni], 16);
            cs[ni] += __shfl_xor(cs[ni], 32);
        }
        if (l4 == 0) {
            #pragma unroll
            for (int ni = 0; ni < 4; ++ni)
                atomicAdd(&rowsum[colBase + wc + ni * 16 + l15], cs[ni]);
        }
    }
}

// ---------------- kernel 3: final scalar reduction -------------------------
__global__ __launch_bounds__(1024)
void finalize_kernel(const float* __restrict__ rowsum,
                     const float* __restrict__ targets, float* __restrict__ out) {
    const int tid = threadIdx.x;
    float s = 0.f;
    #pragma unroll
    for (int t = tid; t < NN; t += 1024)
        s += targets[t] - 10.f - __logf(rowsum[t]);
    #pragma unroll
    for (int off = 1; off <= 32; off <<= 1) s += __shfl_xor(s, off);
    __shared__ float red[16];
    if ((tid & 63) == 0) red[tid >> 6] = s;
    __syncthreads();
    if (tid == 0) {
        float t = 0.f;
        #pragma unroll
        for (int i = 0; i < 16; ++i) t += red[i];
        out[0] = -t / (float)NN;
    }
}

extern "C" void kernel_launch(void* const* d_in, const int* in_sizes, int n_in,
                              void* d_out, int out_size, void* d_ws, size_t ws_size,
                              hipStream_t stream) {
    const float* zi = (const float*)d_in[0];
    const float* zj = (const float*)d_in[1];

    unsigned char* M = (unsigned char*)d_ws;                         // 4 MB fp8
    float* rowsum  = (float*)((char*)d_ws + (size_t)NN * DD);        // 32 KB
    float* targets = rowsum + NN;                                    // 32 KB
    float* out = (float*)d_out;

    normalize_kernel<<<NN / 4, 256, 0, stream>>>(zi, zj, M, rowsum);
    gram_lse_kernel<<<NBLK, 256, 0, stream>>>(M, rowsum, targets);
    finalize_kernel<<<1, 1024, 0, stream>>>(rowsum, targets, out);
}

// Round 9
// 132.582 us; speedup vs baseline: 1.6125x; 1.6125x over previous
//
#include <hip/hip_runtime.h>
#include <hip/hip_bf16.h>
#include <hip/hip_fp8.h>

// SimCLR NT-Xent loss on MI355X.
// loss = -(1/2B) sum_t [ 10*G[t,j0(t)] - (10 + log sum_{j!=t} exp(10*G[t,j]-10)) ]
// where G = M M^T, M = l2norm rows of [z_i; z_j], j0 = (t%B==0) ? 1 : 0.
// Round 9: MX fp8 16x16x128 with the round-7/8 spill fixed. Diagnosis: with
// launch_bounds(256,3) the unified reg budget (~170) couldn't hold acc(64,
// AGPR) + 8 live 8-reg operand tuples(64 VGPR) + addresses -> per-chunk
// scratch spills (545 MB traffic, WRITE_SIZE 316 MB). Fix: (a) bounds
// (256,2) -> ~256 regs/wave; (b) assemble b[4] once per chunk, each a[mi]
// just before use -> max 5 live tuples. Everything else = round 7/8
// (0 bank conflicts and absmax 0.0 both verified there).

#define BB 4096      // batch B
#define DD 512       // feature dim (bytes per row in fp8)
#define NN 8192      // 2B rows of G
#define TILE 128     // block tile (rows x cols)
#define KB 128       // K bytes (=elements) staged per LDS chunk
#define NBLK 2080    // 64*65/2 upper-triangle block tiles

typedef __attribute__((ext_vector_type(2))) int   int2v;   // 8 B
typedef __attribute__((ext_vector_type(8))) int   int8v;   // 32 B (8 VGPR)
typedef __attribute__((ext_vector_type(4))) float f32x4;

#define AS1 __attribute__((address_space(1)))
#define AS3 __attribute__((address_space(3)))
static __device__ __forceinline__ void gload_lds16(const void* g, void* l) {
    __builtin_amdgcn_global_load_lds((const AS1 void*)g, (AS3 void*)l, 16, 0, 0);
}

// ---------------- kernel 1: L2-normalize rows, cast to fp8; zero rowsum ----
// One wave per row. M layout: row r, granule g (16 B), 8 B halves swapped
// when (r>>3)&1 -- lets gram's b64 fragment reads spread banks via row bit 3.
__global__ __launch_bounds__(256)
void normalize_kernel(const float* __restrict__ zi, const float* __restrict__ zj,
                      unsigned char* __restrict__ M, float* __restrict__ rowsum) {
    const int wave = threadIdx.x >> 6;
    const int lane = threadIdx.x & 63;
    const int row  = blockIdx.x * 4 + wave;      // 2048 blocks * 4 rows
    if (threadIdx.x < 4) rowsum[blockIdx.x * 4 + threadIdx.x] = 0.f;
    const float* src = (row < BB) ? (zi + (size_t)row * DD)
                                  : (zj + (size_t)(row - BB) * DD);
    float4 v0 = ((const float4*)src)[lane * 2 + 0];
    float4 v1 = ((const float4*)src)[lane * 2 + 1];
    float ss = v0.x*v0.x + v0.y*v0.y + v0.z*v0.z + v0.w*v0.w
             + v1.x*v1.x + v1.y*v1.y + v1.z*v1.z + v1.w*v1.w;
    #pragma unroll
    for (int off = 1; off <= 32; off <<= 1) ss += __shfl_xor(ss, off);
    const float inv = rsqrtf(ss);
    const float vals[8] = {v0.x*inv, v0.y*inv, v0.z*inv, v0.w*inv,
                           v1.x*inv, v1.y*inv, v1.z*inv, v1.w*inv};
    union { long u; unsigned char b[8]; } pk;
    #pragma unroll
    for (int j = 0; j < 8; ++j)
        pk.b[j] = __hip_cvt_float_to_fp8(vals[j], __HIP_SATFINITE, __HIP_E4M3);
    const int swp = (row >> 3) & 1;              // half-swap inside each granule
    ((long*)(M + (size_t)row * DD))[lane ^ swp] = pk.u;
}

// ---------------- kernel 2: Gram tile + exp row/col sums -------------------
// 2080 blocks, one upper-triangle 128x128 tile each (by >= bx).
// Wave w: rows wr=(w>>1)*64, cols wc=(w&1)*64; 4x4 of 16x16 MFMA tiles,
// one K=128 scaled MFMA per tile per chunk.
// LDS: row-major 128 rows x 128 B, XOR-swizzled 16B granules
//   granule q holds (row=q>>3, g=(q&7)^((q>>3)&7)); gather side inverts the
//   swizzle so global_load_lds's lane-linear dest constraint is satisfied.
__global__ __launch_bounds__(256, 2)
void gram_lse_kernel(const unsigned char* __restrict__ Mg,
                     float* __restrict__ rowsum, float* __restrict__ targets) {
    __shared__ __align__(16) char As[TILE * KB];   // 16 KB
    __shared__ __align__(16) char Bs[TILE * KB];   // 16 KB

    // XCD-banded order: dispatch d -> band d%8 (one XCD), 260 tiles per band.
    const int d = blockIdx.x;
    const int p = (d & 7) * 260 + (d >> 3);
    // triangular decode: p -> (bx, by) with by >= bx
    int by = (int)((sqrtf(8.0f * (float)p + 1.0f) - 1.0f) * 0.5f);
    while ((by + 1) * (by + 2) / 2 <= p) ++by;
    while (by * (by + 1) / 2 > p) --by;
    const int bx = p - by * (by + 1) / 2;

    const int rowBase = bx * TILE;
    const int colBase = by * TILE;
    const bool diag = (bx == by);
    const int tid  = threadIdx.x;
    const int wave = tid >> 6;
    const int lane = tid & 63;
    const int wr = (wave >> 1) * 64;
    const int wc = (wave & 1) * 64;
    const int l15 = lane & 15;
    const int l4  = lane >> 4;          // quad 0..3 (k-window selector)
    const int r7  = l15 & 7;
    const int r3  = (l15 >> 3) & 1;     // row bit 3 -> half-swap key

    // staging gather pattern (constant per thread across issues & k0):
    const int sg  = (tid & 7) ^ ((tid >> 3) & 7);   // source granule within row
    const int sr0 = tid >> 3;                        // source row base (+32/issue)
    const unsigned char* gA0 = Mg + (size_t)(rowBase + sr0) * DD + sg * 16;
    const unsigned char* gB0 = Mg + (size_t)(colBase + sr0) * DD + sg * 16;
    char* lA0 = As + tid * 16;                       // granule q = tid (+256/issue)
    char* lB0 = Bs + tid * 16;

    // fragment addressing: operand row = base+l15, lane k-window = l4*32
    //   -> granules {2*l4, 2*l4+1} (XOR r7), halves XOR r3 (storage half-swap).
    // Per b64: conflict-free (round-7/8 measured SQ_LDS_BANK_CONFLICT=0).
    const int g0off = (((2 * l4 + 0) ^ r7) << 4) | (r3 << 3);
    const int g1off = (((2 * l4 + 1) ^ r7) << 4) | (r3 << 3);
    const int arow0 = (wr + l15) * KB;
    const int brow0 = (wc + l15) * KB;
    const char* BsP = diag ? As : Bs;

    f32x4 acc[4][4] = {};

    for (int k0 = 0; k0 < DD; k0 += KB) {
        __syncthreads();   // previous-iteration LDS reads done
        #pragma unroll
        for (int i = 0; i < 4; ++i)
            gload_lds16(gA0 + k0 + (size_t)i * 32 * DD, lA0 + i * 4096);
        if (!diag) {
            #pragma unroll
            for (int i = 0; i < 4; ++i)
                gload_lds16(gB0 + k0 + (size_t)i * 32 * DD, lB0 + i * 4096);
        }
        __syncthreads();   // drains vmcnt(0): staging complete

        // Operand assembly: logical byte order (g0:h0, g0:h1, g1:h0, g1:h1);
        // stored half at offset (j^r3)*8 is logical half j, so g0off^8 flips
        // to the other logical half. b[4] assembled once (reused by all mi);
        // each a assembled just before its 4 MFMAs -> <=5 live 8-reg tuples.
        int8v b[4];
        #pragma unroll
        for (int ni = 0; ni < 4; ++ni) {
            const char* base = BsP + brow0 + ni * 2048;
            int2v w0 = *(const int2v*)(base + g0off);
            int2v w1 = *(const int2v*)(base + (g0off ^ 8));
            int2v w2 = *(const int2v*)(base + g1off);
            int2v w3 = *(const int2v*)(base + (g1off ^ 8));
            int8v t;
            t[0] = w0[0]; t[1] = w0[1]; t[2] = w1[0]; t[3] = w1[1];
            t[4] = w2[0]; t[5] = w2[1]; t[6] = w3[0]; t[7] = w3[1];
            b[ni] = t;
        }
        #pragma unroll
        for (int mi = 0; mi < 4; ++mi) {
            const char* base = As + arow0 + mi * 2048;
            int2v w0 = *(const int2v*)(base + g0off);
            int2v w1 = *(const int2v*)(base + (g0off ^ 8));
            int2v w2 = *(const int2v*)(base + g1off);
            int2v w3 = *(const int2v*)(base + (g1off ^ 8));
            int8v a;
            a[0] = w0[0]; a[1] = w0[1]; a[2] = w1[0]; a[3] = w1[1];
            a[4] = w2[0]; a[5] = w2[1]; a[6] = w3[0]; a[7] = w3[1];
            #pragma unroll
            for (int ni = 0; ni < 4; ++ni)
                acc[mi][ni] = __builtin_amdgcn_mfma_scale_f32_16x16x128_f8f6f4(
                    a, b[ni], acc[mi][ni],
                    0, 0,          // fmtA=fp8, fmtB=fp8
                    0, 127,        // scaleA: E8M0 127 = 1.0
                    0, 127);       // scaleB: 1.0
        }
    }

    // ---- epilogue ----
    // C/D layout: col = lane&15, row = (lane>>4)*4 + reg  (dtype-independent)
    float cs[4] = {0.f, 0.f, 0.f, 0.f};   // column partials (off-diag tiles)
    #pragma unroll
    for (int mi = 0; mi < 4; ++mi) {
        float rs[4] = {0.f, 0.f, 0.f, 0.f};
        #pragma unroll
        for (int ni = 0; ni < 4; ++ni) {
            const int gcol = colBase + wc + ni * 16 + l15;
            #pragma unroll
            for (int r = 0; r < 4; ++r) {
                const int grow = rowBase + wr + mi * 16 + l4 * 4 + r;
                float logit = 10.f * acc[mi][ni][r];
                float e = __expf(logit - 10.f);
                if (grow == gcol) e = 0.f;     // exclude diagonal exactly
                rs[r] += e;
                cs[ni] += e;
                // targets: rows 0/1 of G give 10*G[t, j0] transposed.
                // Only bx==0 blocks write; disjoint col ranges -> plain store.
                if (rowBase == 0 && grow < 2) {
                    const int j0 = ((gcol & (BB - 1)) == 0) ? 1 : 0;
                    if (grow == j0) targets[gcol] = logit;
                }
            }
        }
        #pragma unroll
        for (int m = 1; m <= 8; m <<= 1)
            #pragma unroll
            for (int r = 0; r < 4; ++r)
                rs[r] += __shfl_xor(rs[r], m);
        if (l15 == 0) {
            #pragma unroll
            for (int r = 0; r < 4; ++r)
                atomicAdd(&rowsum[rowBase + wr + mi * 16 + l4 * 4 + r], rs[r]);
        }
    }
    if (!diag) {
        #pragma unroll
        for (int ni = 0; ni < 4; ++ni) {
            cs[ni] += __shfl_xor(cs[ni], 16);
            cs[ni] += __shfl_xor(cs[ni], 32);
        }
        if (l4 == 0) {
            #pragma unroll
            for (int ni = 0; ni < 4; ++ni)
                atomicAdd(&rowsum[colBase + wc + ni * 16 + l15], cs[ni]);
        }
    }
}

// ---------------- kernel 3: final scalar reduction -------------------------
__global__ __launch_bounds__(1024)
void finalize_kernel(const float* __restrict__ rowsum,
                     const float* __restrict__ targets, float* __restrict__ out) {
    const int tid = threadIdx.x;
    float s = 0.f;
    #pragma unroll
    for (int t = tid; t < NN; t += 1024)
        s += targets[t] - 10.f - __logf(rowsum[t]);
    #pragma unroll
    for (int off = 1; off <= 32; off <<= 1) s += __shfl_xor(s, off);
    __shared__ float red[16];
    if ((tid & 63) == 0) red[tid >> 6] = s;
    __syncthreads();
    if (tid == 0) {
        float t = 0.f;
        #pragma unroll
        for (int i = 0; i < 16; ++i) t += red[i];
        out[0] = -t / (float)NN;
    }
}

extern "C" void kernel_launch(void* const* d_in, const int* in_sizes, int n_in,
                              void* d_out, int out_size, void* d_ws, size_t ws_size,
                              hipStream_t stream) {
    const float* zi = (const float*)d_in[0];
    const float* zj = (const float*)d_in[1];

    unsigned char* M = (unsigned char*)d_ws;                         // 4 MB fp8
    float* rowsum  = (float*)((char*)d_ws + (size_t)NN * DD);        // 32 KB
    float* targets = rowsum + NN;                                    // 32 KB
    float* out = (float*)d_out;

    normalize_kernel<<<NN / 4, 256, 0, stream>>>(zi, zj, M, rowsum);
    gram_lse_kernel<<<NBLK, 256, 0, stream>>>(M, rowsum, targets);
    finalize_kernel<<<1, 1024, 0, stream>>>(rowsum, targets, out);
}